// Round 4
// baseline (296.906 us; speedup 1.0000x reference)
//
#include <hip/hip_runtime.h>
#include <hip/hip_bf16.h>

#define BB 16
#define TT 2048
#define DIMC 512
#define HEADH 64

typedef __attribute__((ext_vector_type(8))) short short8v;   // 8 bf16 (4 VGPRs)
typedef __attribute__((ext_vector_type(4))) float f32x4;     // MFMA C/D

static __device__ __forceinline__ unsigned short f2bf(float f) {
    __hip_bfloat16 h = __float2bfloat16(f);          // RNE, native path
    unsigned short u;
    __builtin_memcpy(&u, &h, 2);
    return u;
}
static __device__ __forceinline__ unsigned int packbf(float lo, float hi) {
    float2 f2; f2.x = lo; f2.y = hi;
    __hip_bfloat162 h2 = __float22bfloat162_rn(f2);  // ideally v_cvt_pk_bf16_f32
    unsigned int u;
    __builtin_memcpy(&u, &h2, 4);
    return u;
}

union bfrag {
    unsigned int u[4];
    short8v v;
};

// ---------------- Kernel 0: W f32 -> bf16, concat [q|k|v] rows -------------
__global__ __launch_bounds__(256) void wcvt_kernel(
    const float* __restrict__ Wq, const float* __restrict__ Wk,
    const float* __restrict__ Wv, unsigned short* __restrict__ wb)
{
    const int idx = blockIdx.x * 256 + threadIdx.x;   // 12288 threads x 8 elems
    const int e   = idx << 3;
    const int row = e >> 9, col = e & 511;
    const float* src = (row < 64) ? Wq : (row < 128) ? Wk : Wv;
    const float* p = src + (size_t)(row & 63) * DIMC + col;
    float4 a = *(const float4*)p;
    float4 b = *(const float4*)(p + 4);
    uint4 o;
    o.x = packbf(a.x, a.y); o.y = packbf(a.z, a.w);
    o.z = packbf(b.x, b.y); o.w = packbf(b.z, b.w);
    *(uint4*)(wb + e) = o;
}

// ---------------- Kernel A: MFMA QKV projection + rotary -------------------
// C^T form: C[h][t] = W(192x512) . x^T, mfma_f32_16x16x32_bf16.
// Block = 3 waves, wave w = matrix (0=q,1=k,2=v). Wave tile: 32 t x 64 h.
__global__ __launch_bounds__(192) void qkv_mfma_kernel(
    const float* __restrict__ x,
    const unsigned short* __restrict__ wb,
    const float* __restrict__ fxr, const float* __restrict__ fxi,
    const float* __restrict__ fyr, const float* __restrict__ fyi,
    unsigned short* __restrict__ qo, unsigned short* __restrict__ ko,
    unsigned short* __restrict__ vt)
{
    const int tid = threadIdx.x;
    const int w   = tid >> 6;          // matrix: 0=q, 1=k, 2=v
    const int l   = tid & 63;
    const int q   = l & 15;
    const int g   = l >> 4;
    const int t0  = blockIdx.x << 5;   // 32 t-rows per block (global over B*T)

    f32x4 acc[2][4];
    #pragma unroll
    for (int i = 0; i < 2; ++i)
        #pragma unroll
        for (int ht = 0; ht < 4; ++ht) acc[i][ht] = (f32x4){0.f, 0.f, 0.f, 0.f};

    const unsigned short* wm = wb + ((size_t)w * 64) * DIMC;
    const float* xr0 = x + (size_t)(t0 + q) * DIMC + 8 * g;
    const float* xr1 = x + (size_t)(t0 + 16 + q) * DIMC + 8 * g;

    #pragma unroll 4
    for (int k0 = 0; k0 < DIMC; k0 += 32) {
        float4 a0 = *(const float4*)(xr0 + k0);
        float4 b0 = *(const float4*)(xr0 + k0 + 4);
        float4 a1 = *(const float4*)(xr1 + k0);
        float4 b1 = *(const float4*)(xr1 + k0 + 4);
        bfrag x0, x1;
        x0.u[0] = packbf(a0.x, a0.y); x0.u[1] = packbf(a0.z, a0.w);
        x0.u[2] = packbf(b0.x, b0.y); x0.u[3] = packbf(b0.z, b0.w);
        x1.u[0] = packbf(a1.x, a1.y); x1.u[1] = packbf(a1.z, a1.w);
        x1.u[2] = packbf(b1.x, b1.y); x1.u[3] = packbf(b1.z, b1.w);

        short8v wf[4];
        #pragma unroll
        for (int ht = 0; ht < 4; ++ht)
            wf[ht] = *(const short8v*)(wm + (size_t)(16 * ht + q) * DIMC + k0 + 8 * g);

        #pragma unroll
        for (int ht = 0; ht < 4; ++ht) {
            acc[0][ht] = __builtin_amdgcn_mfma_f32_16x16x32_bf16(wf[ht], x0.v, acc[0][ht], 0, 0, 0);
            acc[1][ht] = __builtin_amdgcn_mfma_f32_16x16x32_bf16(wf[ht], x1.v, acc[1][ht], 0, 0, 0);
        }
    }

    const float qscale = 1.4426950408889634f / 22.627416997969522f; // log2e/sqrt(512)
    #pragma unroll
    for (int tt2 = 0; tt2 < 2; ++tt2) {
        const int trow = t0 + 16 * tt2 + q;
        const int tl   = trow & (TT - 1);
        if (w == 2) {
            const int b = trow >> 11;
            #pragma unroll
            for (int ht = 0; ht < 4; ++ht) {
                const int d = 16 * ht + 4 * g;
                #pragma unroll
                for (int r = 0; r < 4; ++r)
                    vt[((size_t)(b * HEADH) + d + r) * TT + tl] = f2bf(acc[tt2][ht][r]);
            }
        } else {
            const float sc = (w == 0) ? qscale : 1.f;
            unsigned short* dst = ((w == 0) ? qo : ko) + (size_t)trow * HEADH;
            #pragma unroll
            for (int ht = 0; ht < 4; ++ht) {
                const int hbase = 16 * ht + 4 * g;
                const int half  = hbase >> 5;
                const float* frt = half ? fyr : fxr;
                const float* fit = half ? fyi : fxi;
                const int pi0 = (hbase & 31) >> 1;
                float fr0 = frt[tl * 16 + pi0],     fi0 = fit[tl * 16 + pi0];
                float fr1 = frt[tl * 16 + pi0 + 1], fi1 = fit[tl * 16 + pi0 + 1];
                float e0 = acc[tt2][ht][0] * fr0 - acc[tt2][ht][1] * fi0;
                float e1 = acc[tt2][ht][0] * fi0 + acc[tt2][ht][1] * fr0;
                float e2 = acc[tt2][ht][2] * fr1 - acc[tt2][ht][3] * fi1;
                float e3 = acc[tt2][ht][2] * fi1 + acc[tt2][ht][3] * fr1;
                uint2 ow;
                ow.x = packbf(e0 * sc, e1 * sc);
                ow.y = packbf(e2 * sc, e3 * sc);
                *(uint2*)(dst + hbase) = ow;
            }
        }
    }
}

// ---------------- Kernel B: MFMA flash attention, 4-wave KV-split -----------
// Block = 4 waves; wave w handles kv range [w*512, w*512+512) for the SAME
// 16 q-rows (8 tiles of 64). Inner loop identical to the verified round-2/3
// kernel. Epilogue: LDS combine of 4 partial (m, l, O) triples.
// LDS: per-wave 2KB plds during the loop; after a barrier the same 16.5KB
// region is reused as the combine buffer (o[4][16][64] f32 + ml[4][2][16]).
__global__ __launch_bounds__(256, 8) void attn_mfma_kernel(
    const unsigned short* __restrict__ qws,   // [b][t][64] bf16, pre-scaled
    const unsigned short* __restrict__ kws,   // [b][t][64] bf16
    const unsigned short* __restrict__ vtw,   // [b][d][t]  bf16 (V^T)
    float* __restrict__ out)
{
    __shared__ unsigned int smem[4224];       // 16.5 KB (union: plds | o+ml)

    const int tid = threadIdx.x;
    const int w   = tid >> 6;                 // wave = kv quarter
    const int l   = tid & 63;
    const int q   = l & 15;
    const int g   = l >> 4;
    const int b   = blockIdx.x >> 7;
    const int q0  = (blockIdx.x & 127) << 4;
    const int swz = (q & 7) << 2;             // XOR on word-index bits 2..4

    unsigned int* plds = smem + w * 512;      // 2KB per wave, private

    short8v qf[2];
    {
        const unsigned short* qp = qws + ((size_t)(b * TT + q0 + q)) * HEADH + 8 * g;
        qf[0] = *(const short8v*)(qp);
        qf[1] = *(const short8v*)(qp + 32);
    }

    f32x4 oacc[4];
    #pragma unroll
    for (int mt = 0; mt < 4; ++mt) oacc[mt] = (f32x4){0.f, 0.f, 0.f, 0.f};
    float m = -1e30f, lsum = 0.f;

    const unsigned short* kbase = kws + (size_t)b * TT * HEADH;
    const unsigned short* vbase = vtw + (size_t)b * HEADH * TT;

    const int kvbeg = w << 9;                 // w*512
    for (int kv0 = kvbeg; kv0 < kvbeg + 512; kv0 += 64) {
        f32x4 sacc[4];
        #pragma unroll
        for (int n = 0; n < 4; ++n) {
            const unsigned short* kp = kbase + (size_t)(kv0 + 16 * n + q) * HEADH + 8 * g;
            short8v k0 = *(const short8v*)(kp);
            short8v k1 = *(const short8v*)(kp + 32);
            sacc[n] = (f32x4){0.f, 0.f, 0.f, 0.f};
            sacc[n] = __builtin_amdgcn_mfma_f32_16x16x32_bf16(k0, qf[0], sacc[n], 0, 0, 0);
            sacc[n] = __builtin_amdgcn_mfma_f32_16x16x32_bf16(k1, qf[1], sacc[n], 0, 0, 0);
        }

        short8v vf[2][4];
        #pragma unroll
        for (int s = 0; s < 2; ++s)
            #pragma unroll
            for (int mt = 0; mt < 4; ++mt)
                vf[s][mt] = *(const short8v*)(vbase +
                    (size_t)(16 * mt + q) * TT + kv0 + 32 * s + 8 * g);

        float cmax = sacc[0][0];
        #pragma unroll
        for (int n = 0; n < 4; ++n)
            #pragma unroll
            for (int r = 0; r < 4; ++r) cmax = fmaxf(cmax, sacc[n][r]);
        cmax = fmaxf(cmax, __shfl_xor(cmax, 16));
        cmax = fmaxf(cmax, __shfl_xor(cmax, 32));
        const float mnew = fmaxf(m, cmax);

        float p[4][4];
        float psum = 0.f;
        #pragma unroll
        for (int n = 0; n < 4; ++n)
            #pragma unroll
            for (int r = 0; r < 4; ++r) {
                p[n][r] = exp2f(sacc[n][r] - mnew);
                psum += p[n][r];
            }
        psum += __shfl_xor(psum, 16);
        psum += __shfl_xor(psum, 32);

        const float sc = exp2f(m - mnew);
        if (__any(cmax > m)) {
            #pragma unroll
            for (int mt = 0; mt < 4; ++mt)
                #pragma unroll
                for (int r = 0; r < 4; ++r) oacc[mt][r] *= sc;
        }
        lsum = lsum * sc + psum;
        m = mnew;

        #pragma unroll
        for (int n = 0; n < 4; ++n) {
            uint2 wv;
            wv.x = packbf(p[n][0], p[n][1]);
            wv.y = packbf(p[n][2], p[n][3]);
            *(uint2*)&plds[q * 32 + ((8 * n + 2 * g) ^ swz)] = wv;
        }

        #pragma unroll
        for (int s = 0; s < 2; ++s) {
            short8v pb = *(const short8v*)&plds[q * 32 + ((16 * s + 4 * g) ^ swz)];
            #pragma unroll
            for (int mt = 0; mt < 4; ++mt)
                oacc[mt] = __builtin_amdgcn_mfma_f32_16x16x32_bf16(vf[s][mt], pb,
                                                                   oacc[mt], 0, 0, 0);
        }
    }

    // ---- combine the 4 KV-quarter partials through LDS ----
    __syncthreads();                           // all plds reads done
    float* o_f  = (float*)smem;                // [4][16][64]
    float* ml_f = o_f + 4096;                  // [4][2][16]
    #pragma unroll
    for (int mt = 0; mt < 4; ++mt)
        *(f32x4*)&o_f[(w * 16 + q) * 64 + 16 * mt + 4 * g] = oacc[mt];
    if (g == 0) {
        ml_f[w * 32 + q]      = m;
        ml_f[w * 32 + 16 + q] = lsum;
    }
    __syncthreads();

    const int cq = tid >> 4;                   // 0..15: q row
    const int ch = (tid & 15) << 2;            // 0..60: h group of 4
    float mw[4], lw[4];
    #pragma unroll
    for (int ww = 0; ww < 4; ++ww) {
        mw[ww] = ml_f[ww * 32 + cq];
        lw[ww] = ml_f[ww * 32 + 16 + cq];
    }
    float M = fmaxf(fmaxf(mw[0], mw[1]), fmaxf(mw[2], mw[3]));
    float den = 0.f;
    float num0 = 0.f, num1 = 0.f, num2 = 0.f, num3 = 0.f;
    #pragma unroll
    for (int ww = 0; ww < 4; ++ww) {
        float al = exp2f(mw[ww] - M);
        den += al * lw[ww];
        const float* ov = &o_f[(ww * 16 + cq) * 64 + ch];
        num0 += al * ov[0];
        num1 += al * ov[1];
        num2 += al * ov[2];
        num3 += al * ov[3];
    }
    const float inv = 1.f / den;
    float4 res = make_float4(num0 * inv, num1 * inv, num2 * inv, num3 * inv);
    *(float4*)(out + ((size_t)(b * TT + q0 + cq)) * HEADH + ch) = res;
}

extern "C" void kernel_launch(void* const* d_in, const int* in_sizes, int n_in,
                              void* d_out, int out_size, void* d_ws, size_t ws_size,
                              hipStream_t stream)
{
    const float* x   = (const float*)d_in[0];
    const float* Wq  = (const float*)d_in[1];
    const float* Wk  = (const float*)d_in[2];
    const float* Wv  = (const float*)d_in[3];
    const float* fxr = (const float*)d_in[4];
    const float* fxi = (const float*)d_in[5];
    const float* fyr = (const float*)d_in[6];
    const float* fyi = (const float*)d_in[7];
    float* out = (float*)d_out;

    unsigned short* qo = (unsigned short*)d_ws;                  // 4 MB
    unsigned short* ko = qo + (size_t)BB * TT * HEADH;           // 4 MB
    unsigned short* vt = ko + (size_t)BB * TT * HEADH;           // 4 MB
    unsigned short* wb = vt + (size_t)BB * TT * HEADH;           // 192 KB

    wcvt_kernel<<<48, 256, 0, stream>>>(Wq, Wk, Wv, wb);
    qkv_mfma_kernel<<<(BB * TT) / 32, 192, 0, stream>>>(x, wb, fxr, fxi, fyr, fyi,
                                                        qo, ko, vt);
    attn_mfma_kernel<<<BB * 128, 256, 0, stream>>>(qo, ko, vt, out);
}